// Round 10
// baseline (21.318 us; speedup 1.0000x reference)
//
#include <hip/hip_runtime.h>
#include <math.h>

#define PRE_LEN 64
#define BATCH   1024
#define NNB     256

typedef float v2f __attribute__((ext_vector_type(2)));

// Math (validated R4-R9, absmax 0.0):
//   rotation preserves norm: x^2+y^2 = r2
//   x^6+y^6 = r2*(r2^2 - 3*(x*y)^2),  x*y = dx*dy*cos(2a) - (dx^2-dy^2)*(ca*sa)
//   energy_i/r = 60 * rsq(den^2 * r2); the 60x is applied in the tail.
//
// R10: SINGLE compute dispatch. 256 blocks x 1024 thr = 1 block/CU,
// 16 waves/CU (4/SIMD) — same occupancy and same 32 iters/thread as R8.
// Block = 4 consecutive batches: group g = wave>>2 handles b = 4*bid+g with
// the R8 layout (4 waves/group; lane l: t-pair p=l&31 -> t0=2p,2p+1; chunk
// (l>>5)+2*(wave&3); packed v2f math). The 4 group partials combine in LDS,
// then ONE plain atomicAdd per block (256 total ~ 1.9us by the R2
// calibration of 7.3ns/same-line atomic) replaces the dependent
// reduce-kernel dispatch (~3-4us: drain + launch + latency-bound 1-wave run).
__global__ __launch_bounds__(1024, 4) void field_loss_fused(
    const float* __restrict__ output,   // [PRE_LEN][BATCH][2]
    const float* __restrict__ target,   // [PRE_LEN][BATCH][2]
    const float* __restrict__ nbr,      // [BATCH][NNB][5]
    float* __restrict__ out)            // [1], zeroed by memset node
{
    __shared__ float4 s_nb[4][NNB];     // {nx, ny, cos(2a), ca*sa} per batch
    __shared__ float4 s_red[4][4][32];  // {ex0,ey0,ex1,ey1} per (batch,wave,p)
    __shared__ float  s_sum[4];

    const int tid = threadIdx.x;
    const int l   = tid & 63;
    const int q   = tid >> 6;           // wave 0..15
    const int g   = q >> 2;             // batch group 0..3
    const int qg  = q & 3;              // wave within group
    const int p   = l & 31;             // t-pair index
    const int t0  = 2 * p;
    const int b   = 4 * blockIdx.x + g;

    // Strided output loads issued first (latency hides under staging+sincos).
    const size_t o0 = (size_t)t0 * (BATCH * 2) + (size_t)b * 2;
    const size_t o1 = o0 + (BATCH * 2);
    const float2 a0 = *reinterpret_cast<const float2*>(&output[o0]);
    const float2 a1 = *reinterpret_cast<const float2*>(&output[o1]);
    float2 tg0 = make_float2(0.f, 0.f), tg1 = make_float2(0.f, 0.f);
    if (qg == 0) {                      // target only consumed by group tails
        tg0 = *reinterpret_cast<const float2*>(&target[o0]);
        tg1 = *reinterpret_cast<const float2*>(&target[o1]);
    }

    {   // staging: 1024 threads <-> 4 batches x 256 neighbours, one each
        const int gs = tid >> 8;        // which batch this thread stages
        const int n  = tid & 255;
        const float* pn = nbr + (((size_t)(4 * blockIdx.x + gs)) * NNB + n) * 5;
        const float nx  = pn[0];
        const float ny  = pn[1];
        const float ang = pn[4];
        const float rev = ang * 0.31830988618f;         // (2a)/(2*pi)
        const float c2  = __builtin_amdgcn_cosf(rev);   // cos(2a)
        const float s2  = __builtin_amdgcn_sinf(rev);   // sin(2a)
        s_nb[gs][n] = make_float4(nx, ny, c2, 0.5f * s2);
    }
    __syncthreads();

    const v2f px = { a0.x, a1.x };
    const v2f py = { a0.y, a1.y };

    v2f ex = 0.0f, ey = 0.0f;
    const int n0 = ((l >> 5) + 2 * qg) * 32;  // chunk base: 8 chunks of 32
#pragma unroll 8
    for (int i = 0; i < 32; ++i) {
        const float4 nb = s_nb[g][n0 + i];    // few-addr broadcast (free)
        const v2f dx  = px - nb.x;
        const v2f dy  = py - nb.y;
        const v2f dx2 = dx * dx;
        const v2f pp  = dx * dy;
        const v2f r2  = __builtin_elementwise_fma(dy, dy, dx2);
        const v2f qq  = __builtin_elementwise_fma(dy, -dy, dx2);  // dx^2-dy^2
        const v2f xy  = __builtin_elementwise_fma(pp, (v2f)nb.z, -(qq * nb.w));
        const v2f inr = __builtin_elementwise_fma(xy * -3.0f, xy, r2 * r2);
        const v2f den = __builtin_elementwise_fma(r2, inr, (v2f)6.0f);
        const v2f m2  = den * den * r2;
        const v2f s   = { __builtin_amdgcn_rsqf(m2.x),
                          __builtin_amdgcn_rsqf(m2.y) };
        ex = __builtin_elementwise_fma(s, dx, ex);
        ey = __builtin_elementwise_fma(s, dy, ey);
    }

    // combine half-waves (lane l and l^32 share p, differ in chunk)
    const float ex0 = ex.x + __shfl_xor(ex.x, 32, 64);
    const float ey0 = ey.x + __shfl_xor(ey.x, 32, 64);
    const float ex1 = ex.y + __shfl_xor(ex.y, 32, 64);
    const float ey1 = ey.y + __shfl_xor(ey.y, 32, 64);

    if (l < 32)
        s_red[g][qg][p] = make_float4(ex0, ey0, ex1, ey1);
    __syncthreads();

    if (qg == 0) {                      // one tail wave per batch group
        float tex0 = 0.0f, tey0 = 0.0f, tex1 = 0.0f, tey1 = 0.0f;
        #pragma unroll
        for (int k = 0; k < 4; ++k) {
            const float4 r = s_red[g][k][p];
            tex0 += r.x; tey0 += r.y; tex1 += r.z; tey1 += r.w;
        }
        const float en0 = __builtin_amdgcn_sqrtf(
            __builtin_fmaf(tex0, tex0, tey0 * tey0));
        const float en1 = __builtin_amdgcn_sqrtf(
            __builtin_fmaf(tex1, tex1, tey1 * tey1));

        const float d0x = a0.x - tg0.x, d0y = a0.y - tg0.y;
        const float d1x = a1.x - tg1.x, d1y = a1.y - tg1.y;

        float val = (en0 + en1) * (60.0f / (PRE_LEN * BATCH))
                  + (d0x * d0x + d0y * d0y + d1x * d1x + d1y * d1y)
                    * (1.0f / (PRE_LEN * BATCH * 2));

        // lanes 0-31 hold the 32 distinct vals (32-63 duplicate)
        #pragma unroll
        for (int off = 16; off > 0; off >>= 1)
            val += __shfl_down(val, off, 64);

        if (l == 0)
            s_sum[g] = val;
    }
    __syncthreads();

    if (tid == 0)
        atomicAdd(out, (s_sum[0] + s_sum[1]) + (s_sum[2] + s_sum[3]));
}

extern "C" void kernel_launch(void* const* d_in, const int* in_sizes, int n_in,
                              void* d_out, int out_size, void* d_ws, size_t ws_size,
                              hipStream_t stream) {
    const float* output = (const float*)d_in[0];
    const float* target = (const float*)d_in[1];
    const float* nbr    = (const float*)d_in[2];
    float* out = (float*)d_out;

    // accumulate via atomics; harness doesn't re-poison between replays ->
    // zero d_out every call (tiny 4B fill node, graph-capture safe).
    hipMemsetAsync(out, 0, sizeof(float), stream);
    field_loss_fused<<<dim3(BATCH / 4), dim3(1024), 0, stream>>>(
        output, target, nbr, out);
}

// Round 11
// 14.414 us; speedup vs baseline: 1.4790x; 1.4790x over previous
//
#include <hip/hip_runtime.h>
#include <math.h>

#define PRE_LEN 64
#define BATCH   1024
#define NNB     256

typedef float v2f __attribute__((ext_vector_type(2)));

// Math (validated R4-R10, absmax 0.0):
//   rotation preserves norm: x^2+y^2 = r2
//   x^6+y^6 = r2*(r2^2 - 3*(x*y)^2),  x*y = dx*dy*cos(2a) - (dx^2-dy^2)*(ca*sa)
//   energy_i/r = rsq(den^2*r2); the 60x is applied once in the tail.
//
// R11: extend the R3(8w)->R6(4w) winning axis (fewer, longer waves per
// block at fixed grid) one more step: 1024 blocks x 128 thr (2 waves),
// 128 pairs/thread (64 packed iters). 4 blocks/CU x 2 waves = 2 waves/SIMD;
// unroll-8 ILP covers fma/rsq latency. Tail combine 4-way -> 2-way, staging
// barrier covers 2 waves. Finalize via the proven two-dispatch split
// (every single-dispatch variant falsified: R4 +70us, R5 +25us, R10 +7us).
__global__ __launch_bounds__(128, 2) void field_loss_stage1(
    const float* __restrict__ output,   // [PRE_LEN][BATCH][2]
    const float* __restrict__ target,   // [PRE_LEN][BATCH][2]
    const float* __restrict__ nbr,      // [BATCH][NNB][5]
    float* __restrict__ ws)             // [BATCH] partials
{
    __shared__ float4 s_nb[NNB];        // {nx, ny, cos(2a), ca*sa}
    __shared__ float4 s_red[2][32];     // {ex0,ey0,ex1,ey1} per (wave, p)

    const int b   = blockIdx.x;
    const int tid = threadIdx.x;
    const int l   = tid & 63;
    const int q   = tid >> 6;           // wave 0..1
    const int p   = l & 31;             // t-pair index
    const int t0  = 2 * p;

    // Strided output loads issued first (latency hides under staging+sincos).
    const size_t o0 = (size_t)t0 * (BATCH * 2) + (size_t)b * 2;
    const size_t o1 = o0 + (BATCH * 2);
    const float2 a0 = *reinterpret_cast<const float2*>(&output[o0]);
    const float2 a1 = *reinterpret_cast<const float2*>(&output[o1]);
    float2 tg0 = make_float2(0.f, 0.f), tg1 = make_float2(0.f, 0.f);
    if (q == 0) {                       // target only consumed by the tail wave
        tg0 = *reinterpret_cast<const float2*>(&target[o0]);
        tg1 = *reinterpret_cast<const float2*>(&target[o1]);
    }

    {   // staging: 128 threads stage 2 neighbours each
        const float* pn = nbr + ((size_t)b * NNB + tid) * 5;
        #pragma unroll
        for (int h = 0; h < 2; ++h) {
            const float nx  = pn[0];
            const float ny  = pn[1];
            const float ang = pn[4];
            const float rev = ang * 0.31830988618f;         // (2a)/(2*pi)
            const float c2  = __builtin_amdgcn_cosf(rev);   // cos(2a)
            const float s2  = __builtin_amdgcn_sinf(rev);   // sin(2a)
            s_nb[tid + h * 128] = make_float4(nx, ny, c2, 0.5f * s2);
            pn += 128 * 5;
        }
    }
    __syncthreads();

    const v2f px = { a0.x, a1.x };
    const v2f py = { a0.y, a1.y };

    v2f ex = 0.0f, ey = 0.0f;
    const int n0 = ((l >> 5) + 2 * q) * 64;   // chunk base: 4 chunks of 64
#pragma unroll 8
    for (int i = 0; i < 64; ++i) {
        const float4 nb = s_nb[n0 + i];       // 2-addr broadcast (free, m136)
        const v2f dx  = px - nb.x;
        const v2f dy  = py - nb.y;
        const v2f dx2 = dx * dx;
        const v2f pp  = dx * dy;
        const v2f r2  = __builtin_elementwise_fma(dy, dy, dx2);
        const v2f qq  = __builtin_elementwise_fma(dy, -dy, dx2);  // dx^2-dy^2
        const v2f xy  = __builtin_elementwise_fma(pp, (v2f)nb.z, -(qq * nb.w));
        const v2f inr = __builtin_elementwise_fma(xy * -3.0f, xy, r2 * r2);
        const v2f den = __builtin_elementwise_fma(r2, inr, (v2f)6.0f);
        const v2f m2  = den * den * r2;
        const v2f s   = { __builtin_amdgcn_rsqf(m2.x),
                          __builtin_amdgcn_rsqf(m2.y) };
        ex = __builtin_elementwise_fma(s, dx, ex);
        ey = __builtin_elementwise_fma(s, dy, ey);
    }

    // combine half-waves: lane l and l^32 share p, cover chunks {c, c^1}
    const float ex0 = ex.x + __shfl_xor(ex.x, 32, 64);
    const float ey0 = ey.x + __shfl_xor(ey.x, 32, 64);
    const float ex1 = ex.y + __shfl_xor(ex.y, 32, 64);
    const float ey1 = ey.y + __shfl_xor(ey.y, 32, 64);

    if (l < 32)
        s_red[q][p] = make_float4(ex0, ey0, ex1, ey1);
    __syncthreads();

    if (q == 0) {                       // tail: single wave, 2-way combine
        float tex0 = 0.0f, tey0 = 0.0f, tex1 = 0.0f, tey1 = 0.0f;
        #pragma unroll
        for (int k = 0; k < 2; ++k) {
            const float4 r = s_red[k][p];
            tex0 += r.x; tey0 += r.y; tex1 += r.z; tey1 += r.w;
        }
        const float en0 = __builtin_amdgcn_sqrtf(
            __builtin_fmaf(tex0, tex0, tey0 * tey0));
        const float en1 = __builtin_amdgcn_sqrtf(
            __builtin_fmaf(tex1, tex1, tey1 * tey1));

        const float d0x = a0.x - tg0.x, d0y = a0.y - tg0.y;
        const float d1x = a1.x - tg1.x, d1y = a1.y - tg1.y;

        float val = (en0 + en1) * (60.0f / (PRE_LEN * BATCH))
                  + (d0x * d0x + d0y * d0y + d1x * d1x + d1y * d1y)
                    * (1.0f / (PRE_LEN * BATCH * 2));

        // lanes 0-31 hold the 32 distinct vals (32-63 duplicate)
        #pragma unroll
        for (int off = 16; off > 0; off >>= 1)
            val += __shfl_down(val, off, 64);

        if (l == 0)
            ws[b] = val;                // plain store, one per block
    }
}

// Stage 2: ONE wave, no LDS, no barrier. 1024 floats = 256 float4.
__global__ __launch_bounds__(64) void reduce_kernel(
    const float4* __restrict__ ws4,  // [256]
    float* __restrict__ out)         // [1]
{
    const int l = threadIdx.x;
    const float4 a = ws4[l];
    const float4 b = ws4[l + 64];
    const float4 c = ws4[l + 128];
    const float4 d = ws4[l + 192];
    float v = ((a.x + a.y) + (a.z + a.w)) + ((b.x + b.y) + (b.z + b.w))
            + ((c.x + c.y) + (c.z + c.w)) + ((d.x + d.y) + (d.z + d.w));

    #pragma unroll
    for (int off = 32; off > 0; off >>= 1)
        v += __shfl_down(v, off, 64);

    if (l == 0)
        out[0] = v;
}

extern "C" void kernel_launch(void* const* d_in, const int* in_sizes, int n_in,
                              void* d_out, int out_size, void* d_ws, size_t ws_size,
                              hipStream_t stream) {
    const float* output = (const float*)d_in[0];
    const float* target = (const float*)d_in[1];
    const float* nbr    = (const float*)d_in[2];
    float* out = (float*)d_out;
    float* ws  = (float*)d_ws;      // >= 1024 floats, 16B-aligned

    field_loss_stage1<<<dim3(BATCH), dim3(128), 0, stream>>>(output, target, nbr, ws);
    reduce_kernel<<<dim3(1), dim3(64), 0, stream>>>((const float4*)ws, out);
}